// Round 2
// 530.972 us; speedup vs baseline: 1.1509x; 1.1509x over previous
//
#include <hip/hip_runtime.h>
#include <hip/hip_bf16.h>

#define HID 768
#define WROW 1536   // merge_w row stride (floats)
#define NLAB 64

typedef __attribute__((ext_vector_type(8))) __bf16 bf16x8;
typedef __attribute__((ext_vector_type(4))) float f32x4;

__device__ __forceinline__ bf16x8 pk8(float4 a, float4 b) {
    return (bf16x8){(__bf16)a.x, (__bf16)a.y, (__bf16)a.z, (__bf16)a.w,
                    (__bf16)b.x, (__bf16)b.y, (__bf16)b.z, (__bf16)b.w};
}

// ---------------------------------------------------------------------------
// Kernel 1: P[l][j] = bias[j] + sum_k lf[l][k] * W[j][HID + k]   (all fp32)
// One block per output column j (768 blocks), 256 thr = 64 labels x 4 k-segs.
// W-row staged coalesced into LDS once; lf rows are L2-resident (192 KiB).
// ---------------------------------------------------------------------------
__global__ __launch_bounds__(256) void compute_P_kernel(
    const float* __restrict__ lf,    // [64, 768]
    const float* __restrict__ W,     // [768, 1536]
    const float* __restrict__ bias,  // [768]
    float* __restrict__ P)           // [64, 768]
{
    const int j = blockIdx.x;
    const int t = threadIdx.x;
    __shared__ __align__(16) float wrow[HID];
    if (t < 192)
        *(float4*)(wrow + t * 4) =
            *(const float4*)(W + (size_t)j * WROW + HID + t * 4);
    __syncthreads();

    const int lab = t >> 2;          // 0..63
    const int seg = t & 3;           // k-segment of 192
    const float* lfp = lf + lab * HID + seg * 192;
    const float* wp  = wrow + seg * 192;
    float acc = 0.f;
    #pragma unroll 8
    for (int i = 0; i < 192; i += 4) {
        float4 u = *(const float4*)(lfp + i);
        float4 v = *(const float4*)(wp + i);
        acc += u.x * v.x + u.y * v.y + u.z * v.z + u.w * v.w;
    }
    acc += __shfl_xor(acc, 1);       // reduce the 4-lane k-split
    acc += __shfl_xor(acc, 2);
    if (seg == 0) P[lab * HID + j] = acc + bias[j];
}

// ---------------------------------------------------------------------------
// Kernel 2: out[n][j] = (lab==0) ? A[n][j]
//                     : sum_k bf16(A[n][k])*bf16(W[j][k]) + P[lab-1][j]
// 128x128 tile, BK=32, 256 thr = 4 waves, 4x4 mfma 16x16x32 per wave.
//  * reg-staged fp32 -> bf16 LDS: cvt ONCE per element at stage time,
//    bf16 LDS halves staged bytes and fragment ds_read traffic.
//  * loads for K-step k+1 issued before the barrier -> latency hides
//    under fragment reads + MFMA.
//  * double-buffered LDS, ONE barrier per K-step (24 barriers vs 48).
//    Safety: read of buf p at step i vs next write of buf p at step i+2
//    are separated by the barrier at step i+1.
//  * XCD-chunked block swizzle: the 6 column-blocks sharing an A row-panel
//    become consecutive on one XCD -> A re-reads hit that XCD's L2.
//  * 16B-chunk XOR swizzle (chunk ^= row&3) on the LDS WRITE side;
//    fragment reads land ~4-way instead of 16-way.
// ---------------------------------------------------------------------------
__global__ __launch_bounds__(256) void merge_gemm_kernel(
    const float* __restrict__ A,       // [65536, 768]
    const int* __restrict__ labels,    // [65536]
    const float* __restrict__ W,       // [768, 1536] (left half used)
    const float* __restrict__ P,       // [64, 768]
    float* __restrict__ out,           // [65536, 768]
    const int nwg)
{
    __shared__ __align__(16) unsigned short As[2][128 * 32];  // bf16 bits
    __shared__ __align__(16) unsigned short Bs[2][128 * 32];
    __shared__ int Ls[128];

    // bijective XCD-chunk swizzle (m204 form; nwg = 3072 is 8-divisible)
    int bid = blockIdx.x;
    if ((nwg & 7) == 0) {
        const int q = nwg >> 3;
        bid = (bid & 7) * q + (bid >> 3);
    }
    const int m0 = (bid / (HID / 128)) * 128;
    const int j0 = (bid % (HID / 128)) * 128;

    const int t = threadIdx.x;
    if (t < 128) Ls[t] = labels[m0 + t];

    const int w  = t >> 6;
    const int l  = t & 63;
    const int lm = l & 15;        // row/col inside 16x16 tile
    const int lk = l >> 4;        // k-group 0..3 (8 bf16 each)
    const int qm = (w >> 1) * 64;
    const int qn = (w & 1) * 64;

    // Staging map: thread t -> row sr = t>>2 (and sr+64), chunk sc = t&3
    // (8 floats = one 16B bf16 chunk). Stored chunk position = sc ^ (row&3).
    const int sr = t >> 2;
    const int sc = t & 3;
    const float* gA  = A + (size_t)(m0 + sr) * HID  + sc * 8;
    const float* gA2 = gA + (size_t)64 * HID;
    const float* gB  = W + (size_t)(j0 + sr) * WROW + sc * 8;
    const float* gB2 = gB + (size_t)64 * WROW;
    const int eoff = sr * 32 + ((sc ^ (sr & 3)) * 8);   // bf16-element offset
    // row sr+64 has the same (row&3), so its offset is eoff + 64*32.

    float4 ra0, ra1, ra2, ra3, rb0, rb1, rb2, rb3;
    f32x4 acc[4][4] = {};

#define ISSUE(K) do { \
    ra0 = *(const float4*)(gA  + (K));      ra1 = *(const float4*)(gA  + (K) + 4); \
    ra2 = *(const float4*)(gA2 + (K));      ra3 = *(const float4*)(gA2 + (K) + 4); \
    rb0 = *(const float4*)(gB  + (K));      rb1 = *(const float4*)(gB  + (K) + 4); \
    rb2 = *(const float4*)(gB2 + (K));      rb3 = *(const float4*)(gB2 + (K) + 4); \
} while (0)

    ISSUE(0);
    int p = 0;
    for (int k0 = 0; k0 < HID; k0 += 32) {
        // cvt once + swizzled bf16 LDS write (compiler inserts vmcnt waits)
        *(bf16x8*)&As[p][eoff]        = pk8(ra0, ra1);
        *(bf16x8*)&As[p][eoff + 2048] = pk8(ra2, ra3);
        *(bf16x8*)&Bs[p][eoff]        = pk8(rb0, rb1);
        *(bf16x8*)&Bs[p][eoff + 2048] = pk8(rb2, rb3);
        if (k0 + 32 < HID) ISSUE(k0 + 32);   // issue next tile early
        __syncthreads();   // write(p) visible to all waves

        bf16x8 af[4], bfr[4];
        #pragma unroll
        for (int mi = 0; mi < 4; ++mi) {
            const int r = qm + mi * 16 + lm;
            af[mi] = *(const bf16x8*)&As[p][r * 32 + ((lk ^ (r & 3)) * 8)];
        }
        #pragma unroll
        for (int ni = 0; ni < 4; ++ni) {
            const int r = qn + ni * 16 + lm;
            bfr[ni] = *(const bf16x8*)&Bs[p][r * 32 + ((lk ^ (r & 3)) * 8)];
        }

        #pragma unroll
        for (int mi = 0; mi < 4; ++mi)
            #pragma unroll
            for (int ni = 0; ni < 4; ++ni)
                acc[mi][ni] = __builtin_amdgcn_mfma_f32_16x16x32_bf16(
                    af[mi], bfr[ni], acc[mi][ni], 0, 0, 0);

        p ^= 1;   // next K-step writes the other buffer
    }
#undef ISSUE

    // Epilogue. C/D layout: col = lane&15, row = (lane>>4)*4 + reg  [m89/m91]
    #pragma unroll
    for (int mi = 0; mi < 4; ++mi) {
        const int rowb = qm + mi * 16 + lk * 4;
        #pragma unroll
        for (int r = 0; r < 4; ++r) {
            const int n_tok = m0 + rowb + r;
            const int lab   = Ls[rowb + r];
            const size_t rowoff = (size_t)n_tok * HID;
            #pragma unroll
            for (int ni = 0; ni < 4; ++ni) {
                const int j = j0 + qn + ni * 16 + lm;
                float v;
                if (lab != 0)
                    v = acc[mi][ni][r] + P[(size_t)(lab - 1) * HID + j];
                else
                    v = A[rowoff + j];
                out[rowoff + j] = v;
            }
        }
    }
}

extern "C" void kernel_launch(void* const* d_in, const int* in_sizes, int n_in,
                              void* d_out, int out_size, void* d_ws, size_t ws_size,
                              hipStream_t stream) {
    const float* com    = (const float*)d_in[0];  // [16,4096,768] fp32
    const int*   labels = (const int*)d_in[1];    // [16,4096] int32
    const float* lf     = (const float*)d_in[2];  // [64,768] fp32
    const float* W      = (const float*)d_in[3];  // [768,1536] fp32
    const float* bias   = (const float*)d_in[4];  // [768] fp32
    float* out = (float*)d_out;
    float* P = (float*)d_ws;   // 64*768 fp32 = 192 KiB scratch

    const int n_rows = in_sizes[0] / HID;         // 65536
    compute_P_kernel<<<dim3(HID), dim3(256), 0, stream>>>(lf, W, bias, P);
    const int nwg = (n_rows / 128) * (HID / 128); // 3072
    merge_gemm_kernel<<<dim3(nwg), dim3(256), 0, stream>>>(
        com, labels, W, P, out, nwg);
}